// Round 17
// baseline (359.793 us; speedup 1.0000x reference)
//
#include <hip/hip_runtime.h>
#include <cmath>

#define D  128   // D_EDGE
#define DR 64    // D_RBF
#define NB 32    // nodes per block in stage1

typedef float fx4    __attribute__((ext_vector_type(4)));
typedef float f32x16 __attribute__((ext_vector_type(16)));
typedef short short8v __attribute__((ext_vector_type(8)));
typedef unsigned uix2 __attribute__((ext_vector_type(2)));

__device__ __forceinline__ float ssp_f(float x) {
  // softplus(x) - log(2), numerically stable
  float m = fmaxf(x, 0.0f);
  float t = __expf(-fabsf(x));
  return m + __logf(1.0f + t) - 0.69314718055994531f;
}

__device__ __forceinline__ short f2bf(float f) {   // fp32 -> bf16 (RNE)
  unsigned u = __float_as_uint(f);
  u = (u + 0x7FFFu + ((u >> 16) & 1u)) >> 16;
  return (short)u;
}

// ---------------------------------------------------------------------------
// stage0: W_eff = W_cat[:, :128] @ W_rbf (128x64), b_eff; also bf16 copy.
// ---------------------------------------------------------------------------
__global__ __launch_bounds__(256) void stage0_kernel(
    const float* __restrict__ W_rbf, const float* __restrict__ b_rbf,
    const float* __restrict__ W_cat, const float* __restrict__ b_cat,
    float* __restrict__ weff, unsigned short* __restrict__ weffh,
    float* __restrict__ beff, int write_bf16)
{
  int gid = blockIdx.x * 256 + threadIdx.x;
  if (gid < D * DR) {
    int o = gid >> 6;
    int r = gid & 63;
    float acc = 0.0f;
    #pragma unroll 8
    for (int d = 0; d < D; ++d)
      acc = fmaf(W_cat[o * 384 + d], W_rbf[d * DR + r], acc);
    weff[gid] = acc;
    if (write_bf16) weffh[gid] = (unsigned short)f2bf(acc);
  }
  if (gid < D) {
    float acc = b_cat[gid];
    #pragma unroll 8
    for (int d = 0; d < D; ++d)
      acc = fmaf(b_rbf[d], W_cat[gid * 384 + d], acc);
    beff[gid] = acc;
  }
}

// ---------------------------------------------------------------------------
// stage1: PjH[n][o] = bf16(vi[n] . W_cat[o][128:256])
//         PiH[n][o] = bf16(vi[n] . W_cat[o][256:384])
// ---------------------------------------------------------------------------
__global__ __launch_bounds__(256) void stage1_kernel(
    const float* __restrict__ vi, const float* __restrict__ W_cat,
    unsigned short* __restrict__ PjH, unsigned short* __restrict__ PiH, int N)
{
  __shared__ float vrow[NB * D];
  int base = blockIdx.x * NB;
  int t = threadIdx.x;
  for (int idx = t * 4; idx < NB * D; idx += 1024) {
    int n = base + (idx >> 7);
    float4 v = make_float4(0.f, 0.f, 0.f, 0.f);
    if (n < N) v = *(const float4*)&vi[(long)n * D + (idx & 127)];
    *(float4*)&vrow[idx] = v;
  }
  __syncthreads();

  int o     = t & 127;
  int which = t >> 7;
  const float* w = W_cat + (long)o * 384 + 128 + which * 128;
  unsigned short* P = which ? PiH : PjH;

  float acc[NB];
  #pragma unroll
  for (int n = 0; n < NB; ++n) acc[n] = 0.0f;

  for (int dd = 0; dd < D; dd += 4) {
    float4 wv = *(const float4*)&w[dd];
    #pragma unroll
    for (int n = 0; n < NB; ++n) {
      float4 v = *(const float4*)&vrow[n * D + dd];
      acc[n] = fmaf(wv.x, v.x, acc[n]);
      acc[n] = fmaf(wv.y, v.y, acc[n]);
      acc[n] = fmaf(wv.z, v.z, acc[n]);
      acc[n] = fmaf(wv.w, v.w, acc[n]);
    }
  }
  #pragma unroll
  for (int n = 0; n < NB; ++n) {
    int nn = base + n;
    if (nn < N) P[(long)nn * D + o] = (unsigned short)f2bf(acc[n]);
  }
}

// ---------------------------------------------------------------------------
// MFMA edge kernel v6: OPERAND-SWAPPED. C = W_eff x rbf^T, so C/D
// col = lane&31 = EDGE, row = (reg&3)+8*(reg>>2)+4*half = CHANNEL.
// Each lane owns one edge and 16 channels in contiguous 4-runs =>
// per-lane index loads (no shfl), dwordx2 gathers (4 bf16), dwordx4 stores.
// VMEM instrs/wave ~130 vs R16's ~440 (the R16 result showed bytes are NOT
// the limit; the scalar-gather/store instruction rate is the candidate wall).
// A-frag (weights): A[m=lane&31][k=ks*16+half*8+i]; B-frag (rbf row of my
// edge): B[k][n=lane&31]; same k-bijection both sides => correct product.
// Plain stores (L2 write-combines the 16B runs into full lines); NT on rbf.
// NOTE: never set min-waves launch bounds (R3/R13: forced caps -> 900MB
// scratch spill). Occupancy tiers at VGPR 64/128/256; this sits ~100.
// ---------------------------------------------------------------------------
__global__ __launch_bounds__(256) void edge_mfma_kernel(
    const float* __restrict__ rbf, const int* __restrict__ eidx,
    const unsigned short* __restrict__ weffh, const float* __restrict__ beff,
    const unsigned short* __restrict__ PjH, const unsigned short* __restrict__ PiH,
    float* __restrict__ out, int E)
{
  const int t    = threadIdx.x;
  const int lane = t & 63;
  const int col  = lane & 31;   // edge within tile (B col / C col)
  const int half = lane >> 5;   // k-half / C-row-half
  const long wid  = (long)blockIdx.x * 4 + (t >> 6);
  const long base = wid * 64;
  if (base >= (long)E) return;

  const char* PjB = (const char*)PjH;
  const char* PiB = (const char*)PiH;
  char* outB = (char*)out;

  #pragma unroll
  for (int tile = 0; tile < 2; ++tile) {
    const long tb = base + (long)tile * 32;
    if (tb >= (long)E) break;
    const long e = tb + col;
    const bool oke = e < (long)E;
    const long ec = oke ? e : (long)E - 1;

    // ---- B fragment: my edge's rbf row (fp32 -> bf16), NT ----
    const float* arow = rbf + ec * DR + half * 8;
    short8v Bf[4];
    #pragma unroll
    for (int ks = 0; ks < 4; ++ks) {
      fx4 lo = __builtin_nontemporal_load((const fx4*)&arow[ks * 16]);
      fx4 hi = __builtin_nontemporal_load((const fx4*)&arow[ks * 16 + 4]);
      short8v b;
      b[0] = f2bf(lo.x); b[1] = f2bf(lo.y); b[2] = f2bf(lo.z); b[3] = f2bf(lo.w);
      b[4] = f2bf(hi.x); b[5] = f2bf(hi.y); b[6] = f2bf(hi.z); b[7] = f2bf(hi.w);
      Bf[ks] = b;
    }

    // ---- my edge's node indices (direct, per-lane) ----
    const long jbase = (long)eidx[(long)E + ec] << 8;  // j * 128ch * 2B
    const long ibase = (long)eidx[ec] << 8;            // i * 128ch * 2B
    const long obase = e << 9;                         // e * 128ch * 4B

    #pragma unroll
    for (int ct = 0; ct < 4; ++ct) {
      // A fragment (weights) for this 32-channel tile: m = ct*32 + col
      short8v Af[4];
      #pragma unroll
      for (int ks = 0; ks < 4; ++ks)
        Af[ks] = *(const short8v*)&weffh[(ct * 32 + col) * DR + ks * 16 + half * 8];

      // gathers: 4 channels per instr (dwordx2 of bf16), rows 8qd+4half+0..3
      uix2 gj[4], gi[4];
      fx4 bq[4];
      #pragma unroll
      for (int qd = 0; qd < 4; ++qd) {
        gj[qd] = *(const uix2*)(PjB + jbase + ct * 64 + qd * 16 + half * 8);
        gi[qd] = *(const uix2*)(PiB + ibase + ct * 64 + qd * 16 + half * 8);
        bq[qd] = *(const fx4*)&beff[ct * 32 + qd * 8 + half * 4];
      }
      __builtin_amdgcn_sched_barrier(0);   // keep loads issued before MFMA

      f32x16 acc = (f32x16)(0.0f);
      acc = __builtin_amdgcn_mfma_f32_32x32x16_bf16(Af[0], Bf[0], acc, 0, 0, 0);
      acc = __builtin_amdgcn_mfma_f32_32x32x16_bf16(Af[1], Bf[1], acc, 0, 0, 0);
      acc = __builtin_amdgcn_mfma_f32_32x32x16_bf16(Af[2], Bf[2], acc, 0, 0, 0);
      acc = __builtin_amdgcn_mfma_f32_32x32x16_bf16(Af[3], Bf[3], acc, 0, 0, 0);

      #pragma unroll
      for (int qd = 0; qd < 4; ++qd) {
        const float j0 = __uint_as_float(gj[qd].x << 16);
        const float j1 = __uint_as_float(gj[qd].x & 0xFFFF0000u);
        const float j2 = __uint_as_float(gj[qd].y << 16);
        const float j3 = __uint_as_float(gj[qd].y & 0xFFFF0000u);
        const float i0 = __uint_as_float(gi[qd].x << 16);
        const float i1 = __uint_as_float(gi[qd].x & 0xFFFF0000u);
        const float i2 = __uint_as_float(gi[qd].y << 16);
        const float i3 = __uint_as_float(gi[qd].y & 0xFFFF0000u);
        fx4 v;
        v.x = ssp_f(acc[qd * 4 + 0] + j0 + i0 + bq[qd].x);
        v.y = ssp_f(acc[qd * 4 + 1] + j1 + i1 + bq[qd].y);
        v.z = ssp_f(acc[qd * 4 + 2] + j2 + i2 + bq[qd].z);
        v.w = ssp_f(acc[qd * 4 + 3] + j3 + i3 + bq[qd].w);
        if (oke)
          *(fx4*)(outB + obase + ct * 128 + qd * 32 + half * 16) = v;
      }
    }
  }
}

// ---------------------------------------------------------------------------
// Fallback (only if d_ws is too small): 3 additive passes over out, fp32.
// ---------------------------------------------------------------------------
template<int K, int WS, int WOFF, bool GATHER, bool INIT, bool FINAL>
__global__ __launch_bounds__(256) void pass_kernel(
    const float* __restrict__ src, const int* __restrict__ gidx,
    const float* __restrict__ W, const float* __restrict__ beff,
    float* __restrict__ out, int E)
{
  int e = blockIdx.x * 256 + threadIdx.x;
  if (e >= E) return;
  long rowi = GATHER ? (long)gidx[e] : (long)e;

  float4 rv[K / 4];
  const float4* sp = (const float4*)(src + rowi * K);
  #pragma unroll
  for (int c = 0; c < K / 4; ++c) rv[c] = sp[c];

  float* orow = out + (long)e * D;
  for (int ob = 0; ob < D; ob += 4) {
    float acc[4];
    if (INIT) {
      float4 b4 = *(const float4*)&beff[ob];
      acc[0] = b4.x; acc[1] = b4.y; acc[2] = b4.z; acc[3] = b4.w;
    } else {
      float4 p4 = *(const float4*)&orow[ob];
      acc[0] = p4.x; acc[1] = p4.y; acc[2] = p4.z; acc[3] = p4.w;
    }
    #pragma unroll
    for (int k = 0; k < 4; ++k) {
      const float4* wv = (const float4*)&W[(long)(ob + k) * WS + WOFF];
      float a = acc[k];
      #pragma unroll
      for (int c = 0; c < K / 4; ++c) {
        float4 w4 = wv[c]; float4 r4 = rv[c];
        a = fmaf(w4.x, r4.x, a); a = fmaf(w4.y, r4.y, a);
        a = fmaf(w4.z, r4.z, a); a = fmaf(w4.w, r4.w, a);
      }
      acc[k] = a;
    }
    float4 o4;
    o4.x = FINAL ? ssp_f(acc[0]) : acc[0];
    o4.y = FINAL ? ssp_f(acc[1]) : acc[1];
    o4.z = FINAL ? ssp_f(acc[2]) : acc[2];
    o4.w = FINAL ? ssp_f(acc[3]) : acc[3];
    *(float4*)&orow[ob] = o4;
  }
}

// ---------------------------------------------------------------------------
extern "C" void kernel_launch(void* const* d_in, const int* in_sizes, int n_in,
                              void* d_out, int out_size, void* d_ws, size_t ws_size,
                              hipStream_t stream)
{
  const float* vi    = (const float*)d_in[0];
  const float* rbf   = (const float*)d_in[1];
  const float* W_rbf = (const float*)d_in[2];
  const float* b_rbf = (const float*)d_in[3];
  const float* W_cat = (const float*)d_in[4];
  const float* b_cat = (const float*)d_in[5];
  const int*   eidx  = (const int*)d_in[6];

  const int N = in_sizes[0] / D;
  const int E = in_sizes[6] / 2;
  float* out = (float*)d_out;

  float* ws   = (float*)d_ws;
  float* weff = ws;                               // 8192 floats
  float* beff = ws + D * DR;                      // 128 floats (ends 8320)
  unsigned short* weffh = (unsigned short*)(ws + 8448);   // 8192 ushort
  unsigned short* PjH = (unsigned short*)(ws + 8448 + 4096);  // N*128 ushort
  unsigned short* PiH = PjH + (size_t)N * D;
  size_t need = (8448 + 4096 + (size_t)N * 128) * sizeof(float);

  const int use_fast = (ws_size >= need && E >= 1);
  stage0_kernel<<<32, 256, 0, stream>>>(W_rbf, b_rbf, W_cat, b_cat,
                                        weff, weffh, beff, use_fast);

  if (use_fast) {
    stage1_kernel<<<(N + NB - 1) / NB, 256, 0, stream>>>(vi, W_cat, PjH, PiH, N);
    long waves = ((long)E + 63) / 64;
    int fblocks = (int)((waves + 3) / 4);
    edge_mfma_kernel<<<fblocks, 256, 0, stream>>>(rbf, eidx, weffh, beff,
                                                  PjH, PiH, out, E);
  } else {
    int eblocks = (E + 255) / 256;
    pass_kernel<DR, DR, 0,  false, true,  false><<<eblocks, 256, 0, stream>>>(rbf, nullptr,  weff,  beff, out, E);
    pass_kernel<D, 384, 128, true, false, false><<<eblocks, 256, 0, stream>>>(vi,  eidx + E, W_cat, beff, out, E);
    pass_kernel<D, 384, 256, true, false, true ><<<eblocks, 256, 0, stream>>>(vi,  eidx,     W_cat, beff, out, E);
  }
}

// Round 18
// 275.228 us; speedup vs baseline: 1.3073x; 1.3073x over previous
//
#include <hip/hip_runtime.h>
#include <cmath>

#define D  128   // D_EDGE
#define DR 64    // D_RBF
#define NB 32    // nodes per block in stage1

typedef float fx4    __attribute__((ext_vector_type(4)));
typedef float f32x16 __attribute__((ext_vector_type(16)));
typedef short short8v __attribute__((ext_vector_type(8)));

__device__ __forceinline__ float ssp_f(float x) {
  // softplus(x) - log(2), numerically stable
  float m = fmaxf(x, 0.0f);
  float t = __expf(-fabsf(x));
  return m + __logf(1.0f + t) - 0.69314718055994531f;
}

__device__ __forceinline__ short f2bf(float f) {   // fp32 -> bf16 (RNE)
  unsigned u = __float_as_uint(f);
  u = (u + 0x7FFFu + ((u >> 16) & 1u)) >> 16;
  return (short)u;
}

__device__ __forceinline__ float bf2f(unsigned short h) {  // bf16 -> fp32
  return __uint_as_float(((unsigned)h) << 16);
}

// ---------------------------------------------------------------------------
// Merged stage0+stage1 (independent work items, one launch):
//  blocks [0, nb1): stage1 -> PjH/PiH bf16 tables
//  blocks [nb1, nb1+32): stage0 -> weff/weffh/beff
// ---------------------------------------------------------------------------
__global__ __launch_bounds__(256) void prep_kernel(
    const float* __restrict__ vi, const float* __restrict__ W_cat,
    const float* __restrict__ W_rbf, const float* __restrict__ b_rbf,
    const float* __restrict__ b_cat,
    unsigned short* __restrict__ PjH, unsigned short* __restrict__ PiH,
    float* __restrict__ weff, unsigned short* __restrict__ weffh,
    float* __restrict__ beff, int N, int nb1, int write_bf16)
{
  const int t = threadIdx.x;
  if (blockIdx.x >= nb1) {
    // ---- stage0 ----
    int gid = (blockIdx.x - nb1) * 256 + t;
    if (gid < D * DR) {
      int o = gid >> 6;
      int r = gid & 63;
      float acc = 0.0f;
      #pragma unroll 8
      for (int d = 0; d < D; ++d)
        acc = fmaf(W_cat[o * 384 + d], W_rbf[d * DR + r], acc);
      weff[gid] = acc;
      if (write_bf16) weffh[gid] = (unsigned short)f2bf(acc);
    }
    if (gid < D) {
      float acc = b_cat[gid];
      #pragma unroll 8
      for (int d = 0; d < D; ++d)
        acc = fmaf(b_rbf[d], W_cat[gid * 384 + d], acc);
      beff[gid] = acc;
    }
    return;
  }

  // ---- stage1 ----
  __shared__ float vrow[NB * D];
  int base = blockIdx.x * NB;
  for (int idx = t * 4; idx < NB * D; idx += 1024) {
    int n = base + (idx >> 7);
    float4 v = make_float4(0.f, 0.f, 0.f, 0.f);
    if (n < N) v = *(const float4*)&vi[(long)n * D + (idx & 127)];
    *(float4*)&vrow[idx] = v;
  }
  __syncthreads();

  int o     = t & 127;
  int which = t >> 7;
  const float* w = W_cat + (long)o * 384 + 128 + which * 128;
  unsigned short* P = which ? PiH : PjH;

  float acc[NB];
  #pragma unroll
  for (int n = 0; n < NB; ++n) acc[n] = 0.0f;

  for (int dd = 0; dd < D; dd += 4) {
    float4 wv = *(const float4*)&w[dd];
    #pragma unroll
    for (int n = 0; n < NB; ++n) {
      float4 v = *(const float4*)&vrow[n * D + dd];
      acc[n] = fmaf(wv.x, v.x, acc[n]);
      acc[n] = fmaf(wv.y, v.y, acc[n]);
      acc[n] = fmaf(wv.z, v.z, acc[n]);
      acc[n] = fmaf(wv.w, v.w, acc[n]);
    }
  }
  #pragma unroll
  for (int n = 0; n < NB; ++n) {
    int nn = base + n;
    if (nn < N) P[(long)nn * D + o] = (unsigned short)f2bf(acc[n]);
  }
}

// ---------------------------------------------------------------------------
// MFMA edge kernel (R16 structure, proven 212us, unchanged math) launched as
// ONE-WAVE (64-thread) blocks: no LDS, no intra-block coupling -> fine-grain
// dispatch lets the CP keep CUs filled (39 schedulable units/CU vs 9.8),
// raising real residency toward the 16-wave VGPR cap so the per-ct gather
// latency is TLP-covered. Layout/packing is optimal per R15-R17 ablation:
// full-line coalesced gathers (col=channel on lanes), bf16 tables, NT
// streaming rbf/out.
// NOTE: never set min-waves launch bounds (R3/R13: forced caps -> 900MB
// scratch spill).
// ---------------------------------------------------------------------------
__global__ __launch_bounds__(64) void edge_mfma_kernel(
    const float* __restrict__ rbf, const int* __restrict__ eidx,
    const unsigned short* __restrict__ weffh, const float* __restrict__ beff,
    const unsigned short* __restrict__ PjH, const unsigned short* __restrict__ PiH,
    float* __restrict__ out, int E)
{
  const int lane = threadIdx.x & 63;
  const int row  = lane & 31;   // A row / B col / C col (channel)
  const int half = lane >> 5;   // k-half selector
  const long base = (long)blockIdx.x * 64;
  if (base >= (long)E) return;

  // B fragments: B[k][n] = weff[n*64+k] (bf16), n=ct*32+row, k=ks*16+8*half+i
  short8v B[4][4];
  #pragma unroll
  for (int ct = 0; ct < 4; ++ct) {
    #pragma unroll
    for (int ks = 0; ks < 4; ++ks)
      B[ct][ks] = *(const short8v*)&weffh[(ct * 32 + row) * DR + ks * 16 + half * 8];
  }
  float bias[4];
  #pragma unroll
  for (int ct = 0; ct < 4; ++ct) bias[ct] = beff[ct * 32 + row];

  #pragma unroll
  for (int tile = 0; tile < 2; ++tile) {
    const long tb = base + (long)tile * 32;
    if (tb >= (long)E) break;
    long er = tb + row; if (er > (long)E - 1) er = (long)E - 1;

    // A fragments straight from global (fp32 -> bf16), NT (read-once stream)
    const float* arow = rbf + er * DR + half * 8;
    short8v A[4];
    #pragma unroll
    for (int ks = 0; ks < 4; ++ks) {
      fx4 lo = __builtin_nontemporal_load((const fx4*)&arow[ks * 16]);
      fx4 hi = __builtin_nontemporal_load((const fx4*)&arow[ks * 16 + 4]);
      short8v a;
      a[0] = f2bf(lo.x); a[1] = f2bf(lo.y); a[2] = f2bf(lo.z); a[3] = f2bf(lo.w);
      a[4] = f2bf(hi.x); a[5] = f2bf(hi.y); a[6] = f2bf(hi.z); a[7] = f2bf(hi.w);
      A[ks] = a;
    }

    // per-lane edge indices for this tile (lane's row = local edge id)
    const int iv = eidx[er];            // edge_index[0] -> h_i -> Pi
    const int jv = eidx[(long)E + er];  // edge_index[1] -> h_j -> Pj

    #pragma unroll
    for (int ct = 0; ct < 4; ++ct) {
      // gathers: 32 bf16 loads in flight (full-line coalesced per instr)
      float gj[16], gi[16];
      #pragma unroll
      for (int reg = 0; reg < 16; ++reg) {
        const int erl = (reg & 3) + 8 * (reg >> 2) + 4 * half;
        const int j = __shfl(jv, erl);
        const int i = __shfl(iv, erl);
        gj[reg] = bf2f(PjH[(long)j * D + ct * 32 + row]);
        gi[reg] = bf2f(PiH[(long)i * D + ct * 32 + row]);
      }
      __builtin_amdgcn_sched_barrier(0);   // keep gather issue ahead of MFMA

      f32x16 acc = (f32x16)(0.0f);
      acc = __builtin_amdgcn_mfma_f32_32x32x16_bf16(A[0], B[ct][0], acc, 0, 0, 0);
      acc = __builtin_amdgcn_mfma_f32_32x32x16_bf16(A[1], B[ct][1], acc, 0, 0, 0);
      acc = __builtin_amdgcn_mfma_f32_32x32x16_bf16(A[2], B[ct][2], acc, 0, 0, 0);
      acc = __builtin_amdgcn_mfma_f32_32x32x16_bf16(A[3], B[ct][3], acc, 0, 0, 0);

      #pragma unroll
      for (int reg = 0; reg < 16; ++reg) {
        const int erl = (reg & 3) + 8 * (reg >> 2) + 4 * half;
        const long ge = tb + erl;
        const float v = ssp_f(acc[reg] + gj[reg] + gi[reg] + bias[ct]);
        if (ge < (long)E)
          __builtin_nontemporal_store(v, &out[ge * D + ct * 32 + row]);
      }
    }
  }
}

// ---------------------------------------------------------------------------
// Fallback (only if d_ws is too small): 3 additive passes over out, fp32.
// ---------------------------------------------------------------------------
template<int K, int WS, int WOFF, bool GATHER, bool INIT, bool FINAL>
__global__ __launch_bounds__(256) void pass_kernel(
    const float* __restrict__ src, const int* __restrict__ gidx,
    const float* __restrict__ W, const float* __restrict__ beff,
    float* __restrict__ out, int E)
{
  int e = blockIdx.x * 256 + threadIdx.x;
  if (e >= E) return;
  long rowi = GATHER ? (long)gidx[e] : (long)e;

  float4 rv[K / 4];
  const float4* sp = (const float4*)(src + rowi * K);
  #pragma unroll
  for (int c = 0; c < K / 4; ++c) rv[c] = sp[c];

  float* orow = out + (long)e * D;
  for (int ob = 0; ob < D; ob += 4) {
    float acc[4];
    if (INIT) {
      float4 b4 = *(const float4*)&beff[ob];
      acc[0] = b4.x; acc[1] = b4.y; acc[2] = b4.z; acc[3] = b4.w;
    } else {
      float4 p4 = *(const float4*)&orow[ob];
      acc[0] = p4.x; acc[1] = p4.y; acc[2] = p4.z; acc[3] = p4.w;
    }
    #pragma unroll
    for (int k = 0; k < 4; ++k) {
      const float4* wv = (const float4*)&W[(long)(ob + k) * WS + WOFF];
      float a = acc[k];
      #pragma unroll
      for (int c = 0; c < K / 4; ++c) {
        float4 w4 = wv[c]; float4 r4 = rv[c];
        a = fmaf(w4.x, r4.x, a); a = fmaf(w4.y, r4.y, a);
        a = fmaf(w4.z, r4.z, a); a = fmaf(w4.w, r4.w, a);
      }
      acc[k] = a;
    }
    float4 o4;
    o4.x = FINAL ? ssp_f(acc[0]) : acc[0];
    o4.y = FINAL ? ssp_f(acc[1]) : acc[1];
    o4.z = FINAL ? ssp_f(acc[2]) : acc[2];
    o4.w = FINAL ? ssp_f(acc[3]) : acc[3];
    *(float4*)&orow[ob] = o4;
  }
}

// ---------------------------------------------------------------------------
extern "C" void kernel_launch(void* const* d_in, const int* in_sizes, int n_in,
                              void* d_out, int out_size, void* d_ws, size_t ws_size,
                              hipStream_t stream)
{
  const float* vi    = (const float*)d_in[0];
  const float* rbf   = (const float*)d_in[1];
  const float* W_rbf = (const float*)d_in[2];
  const float* b_rbf = (const float*)d_in[3];
  const float* W_cat = (const float*)d_in[4];
  const float* b_cat = (const float*)d_in[5];
  const int*   eidx  = (const int*)d_in[6];

  const int N = in_sizes[0] / D;
  const int E = in_sizes[6] / 2;
  float* out = (float*)d_out;

  float* ws   = (float*)d_ws;
  float* weff = ws;                               // 8192 floats
  float* beff = ws + D * DR;                      // 128 floats (ends 8320)
  unsigned short* weffh = (unsigned short*)(ws + 8448);   // 8192 ushort
  unsigned short* PjH = (unsigned short*)(ws + 8448 + 4096);  // N*128 ushort
  unsigned short* PiH = PjH + (size_t)N * D;
  size_t need = (8448 + 4096 + (size_t)N * 128) * sizeof(float);

  const int use_fast = (ws_size >= need && E >= 1);

  if (use_fast) {
    int nb1 = (N + NB - 1) / NB;
    prep_kernel<<<nb1 + 32, 256, 0, stream>>>(vi, W_cat, W_rbf, b_rbf, b_cat,
                                              PjH, PiH, weff, weffh, beff,
                                              N, nb1, 1);
    int fblocks = (int)(((long)E + 63) / 64);   // one wave (64 edges) per block
    edge_mfma_kernel<<<fblocks, 64, 0, stream>>>(rbf, eidx, weffh, beff,
                                                 PjH, PiH, out, E);
  } else {
    prep_kernel<<<32, 256, 0, stream>>>(vi, W_cat, W_rbf, b_rbf, b_cat,
                                        PjH, PiH, weff, weffh, beff,
                                        N, 0, 0);
    int eblocks = (E + 255) / 256;
    pass_kernel<DR, DR, 0,  false, true,  false><<<eblocks, 256, 0, stream>>>(rbf, nullptr,  weff,  beff, out, E);
    pass_kernel<D, 384, 128, true, false, false><<<eblocks, 256, 0, stream>>>(vi,  eidx + E, W_cat, beff, out, E);
    pass_kernel<D, 384, 256, true, false, true ><<<eblocks, 256, 0, stream>>>(vi,  eidx,     W_cat, beff, out, E);
  }
}

// Round 19
// 245.775 us; speedup vs baseline: 1.4639x; 1.1198x over previous
//
#include <hip/hip_runtime.h>
#include <cmath>

#define D  128   // D_EDGE
#define DR 64    // D_RBF

typedef float fx4    __attribute__((ext_vector_type(4)));
typedef float f32x16 __attribute__((ext_vector_type(16)));
typedef short short8v __attribute__((ext_vector_type(8)));

__device__ __forceinline__ float ssp_f(float x) {
  // softplus(x) - log(2), numerically stable
  float m = fmaxf(x, 0.0f);
  float t = __expf(-fabsf(x));
  return m + __logf(1.0f + t) - 0.69314718055994531f;
}

__device__ __forceinline__ short f2bf(float f) {   // fp32 -> bf16 (RNE)
  unsigned u = __float_as_uint(f);
  u = (u + 0x7FFFu + ((u >> 16) & 1u)) >> 16;
  return (short)u;
}

__device__ __forceinline__ float bf2f(unsigned short h) {  // bf16 -> fp32
  return __uint_as_float(((unsigned)h) << 16);
}

__device__ __forceinline__ short8v cvt8(const float* p) {  // 8 f32 -> bf16x8
  fx4 lo = *(const fx4*)p;
  fx4 hi = *(const fx4*)(p + 4);
  short8v r;
  r[0] = f2bf(lo.x); r[1] = f2bf(lo.y); r[2] = f2bf(lo.z); r[3] = f2bf(lo.w);
  r[4] = f2bf(hi.x); r[5] = f2bf(hi.y); r[6] = f2bf(hi.z); r[7] = f2bf(hi.w);
  return r;
}

// ---------------------------------------------------------------------------
// prep kernel (one launch, two independent block roles):
//  blocks [0, nbt): MFMA table GEMM -> PjH/PiH bf16
//    PjH[n][o] = bf16(vi[n] . W_cat[o][128:256])
//    PiH[n][o] = bf16(vi[n] . W_cat[o][256:384])
//    Same 32x32x16 pattern as the edge kernel (A=vi rows m=node, B=W_cat
//    slice n=chan, k-bijection k=ks*16+half*8+i both sides; C/D col=chan).
//  blocks [nbt, nbt+32): stage0 -> weff (fp32+bf16), beff.
// ---------------------------------------------------------------------------
__global__ __launch_bounds__(256) void prep_kernel(
    const float* __restrict__ vi, const float* __restrict__ W_cat,
    const float* __restrict__ W_rbf, const float* __restrict__ b_rbf,
    const float* __restrict__ b_cat,
    unsigned short* __restrict__ PjH, unsigned short* __restrict__ PiH,
    float* __restrict__ weff, unsigned short* __restrict__ weffh,
    float* __restrict__ beff, int N, int nbt, int write_bf16)
{
  const int t = threadIdx.x;
  if ((int)blockIdx.x >= nbt) {
    // ---- stage0 ----
    int gid = ((int)blockIdx.x - nbt) * 256 + t;
    if (gid < D * DR) {
      int o = gid >> 6;
      int r = gid & 63;
      float acc = 0.0f;
      #pragma unroll 8
      for (int d = 0; d < D; ++d)
        acc = fmaf(W_cat[o * 384 + d], W_rbf[d * DR + r], acc);
      weff[gid] = acc;
      if (write_bf16) weffh[gid] = (unsigned short)f2bf(acc);
    }
    if (gid < D) {
      float acc = b_cat[gid];
      #pragma unroll 8
      for (int d = 0; d < D; ++d)
        acc = fmaf(b_rbf[d], W_cat[gid * 384 + d], acc);
      beff[gid] = acc;
    }
    return;
  }

  // ---- MFMA table GEMM ----
  const int lane = t & 63;
  const int col  = lane & 31;   // A node row / B chan col / C col
  const int half = lane >> 5;   // k-half selector
  const long wid  = (long)blockIdx.x * 4 + (t >> 6);
  const long base = wid * 64;
  if (base >= (long)N) return;

  #pragma unroll
  for (int tile = 0; tile < 2; ++tile) {
    const long tb = base + (long)tile * 32;
    if (tb >= (long)N) break;
    long nr = tb + col; if (nr > (long)N - 1) nr = (long)N - 1;

    // A fragments: my node's vi row (fp32 -> bf16), K=128 -> 8 frags
    const float* arow = vi + nr * D + half * 8;
    short8v A[8];
    #pragma unroll
    for (int ks = 0; ks < 8; ++ks)
      A[ks] = cvt8(&arow[ks * 16]);

    #pragma unroll
    for (int ct = 0; ct < 8; ++ct) {
      const int off = 128 + (ct >> 2) * 128;        // 128: Pj slice, 256: Pi
      const int o   = (ct & 3) * 32 + col;          // output channel
      const float* wrow = W_cat + (long)o * 384 + off + half * 8;

      f32x16 acc = (f32x16)(0.0f);
      #pragma unroll
      for (int ks = 0; ks < 8; ++ks) {
        short8v Bv = cvt8(&wrow[ks * 16]);          // W_cat slice, L2-resident
        acc = __builtin_amdgcn_mfma_f32_32x32x16_bf16(A[ks], Bv, acc, 0, 0, 0);
      }

      unsigned short* P = (ct < 4) ? PjH : PiH;
      const int cb = (ct & 3) * 32;
      #pragma unroll
      for (int reg = 0; reg < 16; ++reg) {
        const int erl = (reg & 3) + 8 * (reg >> 2) + 4 * half;
        const long nn = tb + erl;
        if (nn < (long)N)
          P[nn * D + cb + col] = (unsigned short)f2bf(acc[reg]);
      }
    }
  }
}

// ---------------------------------------------------------------------------
// MFMA edge kernel (R16/R18 structure, proven ~207us, UNCHANGED math).
// One-wave blocks; full-line coalesced gathers (col=channel on lanes),
// bf16 tables, NT streaming rbf/out.
// NOTE: never set min-waves launch bounds (R3/R13: forced caps -> 900MB
// scratch spill).
// ---------------------------------------------------------------------------
__global__ __launch_bounds__(64) void edge_mfma_kernel(
    const float* __restrict__ rbf, const int* __restrict__ eidx,
    const unsigned short* __restrict__ weffh, const float* __restrict__ beff,
    const unsigned short* __restrict__ PjH, const unsigned short* __restrict__ PiH,
    float* __restrict__ out, int E)
{
  const int lane = threadIdx.x & 63;
  const int row  = lane & 31;   // A row / B col / C col (channel)
  const int half = lane >> 5;   // k-half selector
  const long base = (long)blockIdx.x * 64;
  if (base >= (long)E) return;

  // B fragments: B[k][n] = weff[n*64+k] (bf16), n=ct*32+row, k=ks*16+8*half+i
  short8v B[4][4];
  #pragma unroll
  for (int ct = 0; ct < 4; ++ct) {
    #pragma unroll
    for (int ks = 0; ks < 4; ++ks)
      B[ct][ks] = *(const short8v*)&weffh[(ct * 32 + row) * DR + ks * 16 + half * 8];
  }
  float bias[4];
  #pragma unroll
  for (int ct = 0; ct < 4; ++ct) bias[ct] = beff[ct * 32 + row];

  #pragma unroll
  for (int tile = 0; tile < 2; ++tile) {
    const long tb = base + (long)tile * 32;
    if (tb >= (long)E) break;
    long er = tb + row; if (er > (long)E - 1) er = (long)E - 1;

    // A fragments straight from global (fp32 -> bf16), NT (read-once stream)
    const float* arow = rbf + er * DR + half * 8;
    short8v A[4];
    #pragma unroll
    for (int ks = 0; ks < 4; ++ks) {
      fx4 lo = __builtin_nontemporal_load((const fx4*)&arow[ks * 16]);
      fx4 hi = __builtin_nontemporal_load((const fx4*)&arow[ks * 16 + 4]);
      short8v a;
      a[0] = f2bf(lo.x); a[1] = f2bf(lo.y); a[2] = f2bf(lo.z); a[3] = f2bf(lo.w);
      a[4] = f2bf(hi.x); a[5] = f2bf(hi.y); a[6] = f2bf(hi.z); a[7] = f2bf(hi.w);
      A[ks] = a;
    }

    // per-lane edge indices for this tile (lane's row = local edge id)
    const int iv = eidx[er];            // edge_index[0] -> h_i -> Pi
    const int jv = eidx[(long)E + er];  // edge_index[1] -> h_j -> Pj

    #pragma unroll
    for (int ct = 0; ct < 4; ++ct) {
      // gathers: 32 bf16 loads in flight (full-line coalesced per instr)
      float gj[16], gi[16];
      #pragma unroll
      for (int reg = 0; reg < 16; ++reg) {
        const int erl = (reg & 3) + 8 * (reg >> 2) + 4 * half;
        const int j = __shfl(jv, erl);
        const int i = __shfl(iv, erl);
        gj[reg] = bf2f(PjH[(long)j * D + ct * 32 + row]);
        gi[reg] = bf2f(PiH[(long)i * D + ct * 32 + row]);
      }
      __builtin_amdgcn_sched_barrier(0);   // keep gather issue ahead of MFMA

      f32x16 acc = (f32x16)(0.0f);
      acc = __builtin_amdgcn_mfma_f32_32x32x16_bf16(A[0], B[ct][0], acc, 0, 0, 0);
      acc = __builtin_amdgcn_mfma_f32_32x32x16_bf16(A[1], B[ct][1], acc, 0, 0, 0);
      acc = __builtin_amdgcn_mfma_f32_32x32x16_bf16(A[2], B[ct][2], acc, 0, 0, 0);
      acc = __builtin_amdgcn_mfma_f32_32x32x16_bf16(A[3], B[ct][3], acc, 0, 0, 0);

      #pragma unroll
      for (int reg = 0; reg < 16; ++reg) {
        const int erl = (reg & 3) + 8 * (reg >> 2) + 4 * half;
        const long ge = tb + erl;
        const float v = ssp_f(acc[reg] + gj[reg] + gi[reg] + bias[ct]);
        if (ge < (long)E)
          __builtin_nontemporal_store(v, &out[ge * D + ct * 32 + row]);
      }
    }
  }
}

// ---------------------------------------------------------------------------
// Fallback (only if d_ws is too small): 3 additive passes over out, fp32.
// ---------------------------------------------------------------------------
template<int K, int WS, int WOFF, bool GATHER, bool INIT, bool FINAL>
__global__ __launch_bounds__(256) void pass_kernel(
    const float* __restrict__ src, const int* __restrict__ gidx,
    const float* __restrict__ W, const float* __restrict__ beff,
    float* __restrict__ out, int E)
{
  int e = blockIdx.x * 256 + threadIdx.x;
  if (e >= E) return;
  long rowi = GATHER ? (long)gidx[e] : (long)e;

  float4 rv[K / 4];
  const float4* sp = (const float4*)(src + rowi * K);
  #pragma unroll
  for (int c = 0; c < K / 4; ++c) rv[c] = sp[c];

  float* orow = out + (long)e * D;
  for (int ob = 0; ob < D; ob += 4) {
    float acc[4];
    if (INIT) {
      float4 b4 = *(const float4*)&beff[ob];
      acc[0] = b4.x; acc[1] = b4.y; acc[2] = b4.z; acc[3] = b4.w;
    } else {
      float4 p4 = *(const float4*)&orow[ob];
      acc[0] = p4.x; acc[1] = p4.y; acc[2] = p4.z; acc[3] = p4.w;
    }
    #pragma unroll
    for (int k = 0; k < 4; ++k) {
      const float4* wv = (const float4*)&W[(long)(ob + k) * WS + WOFF];
      float a = acc[k];
      #pragma unroll
      for (int c = 0; c < K / 4; ++c) {
        float4 w4 = wv[c]; float4 r4 = rv[c];
        a = fmaf(w4.x, r4.x, a); a = fmaf(w4.y, r4.y, a);
        a = fmaf(w4.z, r4.z, a); a = fmaf(w4.w, r4.w, a);
      }
      acc[k] = a;
    }
    float4 o4;
    o4.x = FINAL ? ssp_f(acc[0]) : acc[0];
    o4.y = FINAL ? ssp_f(acc[1]) : acc[1];
    o4.z = FINAL ? ssp_f(acc[2]) : acc[2];
    o4.w = FINAL ? ssp_f(acc[3]) : acc[3];
    *(float4*)&orow[ob] = o4;
  }
}

// ---------------------------------------------------------------------------
extern "C" void kernel_launch(void* const* d_in, const int* in_sizes, int n_in,
                              void* d_out, int out_size, void* d_ws, size_t ws_size,
                              hipStream_t stream)
{
  const float* vi    = (const float*)d_in[0];
  const float* rbf   = (const float*)d_in[1];
  const float* W_rbf = (const float*)d_in[2];
  const float* b_rbf = (const float*)d_in[3];
  const float* W_cat = (const float*)d_in[4];
  const float* b_cat = (const float*)d_in[5];
  const int*   eidx  = (const int*)d_in[6];

  const int N = in_sizes[0] / D;
  const int E = in_sizes[6] / 2;
  float* out = (float*)d_out;

  float* ws   = (float*)d_ws;
  float* weff = ws;                               // 8192 floats
  float* beff = ws + D * DR;                      // 128 floats (ends 8320)
  unsigned short* weffh = (unsigned short*)(ws + 8448);   // 8192 ushort
  unsigned short* PjH = (unsigned short*)(ws + 8448 + 4096);  // N*128 ushort
  unsigned short* PiH = PjH + (size_t)N * D;
  size_t need = (8448 + 4096 + (size_t)N * 128) * sizeof(float);

  const int use_fast = (ws_size >= need && E >= 1);

  if (use_fast) {
    long twaves = ((long)N + 63) / 64;
    int nbt = (int)((twaves + 3) / 4);           // table-GEMM blocks
    prep_kernel<<<nbt + 32, 256, 0, stream>>>(vi, W_cat, W_rbf, b_rbf, b_cat,
                                              PjH, PiH, weff, weffh, beff,
                                              N, nbt, 1);
    int fblocks = (int)(((long)E + 63) / 64);    // one wave (64 edges) / block
    edge_mfma_kernel<<<fblocks, 64, 0, stream>>>(rbf, eidx, weffh, beff,
                                                 PjH, PiH, out, E);
  } else {
    prep_kernel<<<32, 256, 0, stream>>>(vi, W_cat, W_rbf, b_rbf, b_cat,
                                        PjH, PiH, weff, weffh, beff,
                                        N, 0, 0);
    int eblocks = (E + 255) / 256;
    pass_kernel<DR, DR, 0,  false, true,  false><<<eblocks, 256, 0, stream>>>(rbf, nullptr,  weff,  beff, out, E);
    pass_kernel<D, 384, 128, true, false, false><<<eblocks, 256, 0, stream>>>(vi,  eidx + E, W_cat, beff, out, E);
    pass_kernel<D, 384, 256, true, false, true ><<<eblocks, 256, 0, stream>>>(vi,  eidx,     W_cat, beff, out, E);
  }
}